// Round 2
// baseline (388.798 us; speedup 1.0000x reference)
//
#include <hip/hip_runtime.h>
#include <hip/hip_bf16.h>
#include <math.h>

typedef short bf16x8 __attribute__((ext_vector_type(8)));
typedef float f32x4 __attribute__((ext_vector_type(4)));
typedef unsigned short u16;
typedef u16 u16x4 __attribute__((ext_vector_type(4)));
typedef u16 u16x8 __attribute__((ext_vector_type(8)));

#define DEV static __device__ __forceinline__

DEV float bf2f(u16 u) { union { unsigned int i; float f; } v; v.i = ((unsigned int)u) << 16; return v.f; }
DEV u16 f2bf(float f) {
  union { float fl; unsigned int i; } v; v.fl = f;
  return (u16)((v.i + 0x7FFFu + ((v.i >> 16) & 1u)) >> 16);
}

// ---------------- prep: x->bf16, bias concat, rope tables (fp64 trig) ----------------
__global__ __launch_bounds__(256) void prep_kernel(
    const float* __restrict__ x, const float* __restrict__ bq,
    const float* __restrict__ bk, const float* __restrict__ bv,
    float* __restrict__ biascat, float* __restrict__ cosT, float* __restrict__ sinT,
    u16* __restrict__ xbf)
{
  int idx = blockIdx.x * 256 + threadIdx.x;
  const int NX = (4096 * 1024) / 4;
  if (idx < NX) {
    const float4 v = ((const float4*)x)[idx];
    u16x4 o;
    o[0] = f2bf(v.x); o[1] = f2bf(v.y); o[2] = f2bf(v.z); o[3] = f2bf(v.w);
    *((u16x4*)xbf + idx) = o;
  } else if (idx < NX + 1536) {
    int n = idx - NX;
    biascat[n] = (n < 1024) ? bq[n] : (n < 1280 ? bk[n - 1024] : bv[n - 1280]);
  } else if (idx < NX + 1536 + 65536) {
    int e = idx - NX - 1536;
    int t = e >> 5, dh = e & 31;
    double invf = pow(10000.0, -(double)(dh >> 1) / 16.0);
    double ang = (double)t * invf;
    cosT[e] = (float)cos(ang);
    sinT[e] = (float)sin(ang);
  }
}

// ---------------- weight transpose+convert ----------------
__global__ __launch_bounds__(256) void wtrans_kernel(
    const float* __restrict__ wq, const float* __restrict__ wk,
    const float* __restrict__ wv, const float* __restrict__ wo,
    u16* __restrict__ wcat, u16* __restrict__ wot)
{
  const int z = blockIdx.z;
  const float* src; u16* dst; int N; int roff;
  if (z == 0)      { src = wq; dst = wcat; N = 1024; roff = 0; }
  else if (z == 1) { src = wk; dst = wcat; N = 256;  roff = 1024; }
  else if (z == 2) { src = wv; dst = wcat; N = 256;  roff = 1280; }
  else             { src = wo; dst = wot;  N = 1024; roff = 0; }
  const int n0 = blockIdx.x << 5;
  if (n0 >= N) return;
  const int k0 = blockIdx.y << 5;
  const int tx = threadIdx.x & 31, ty = threadIdx.x >> 5;
  __shared__ float tile[32][33];
#pragma unroll
  for (int r = 0; r < 32; r += 8)
    tile[ty + r][tx] = src[(size_t)(k0 + ty + r) * N + n0 + tx];
  __syncthreads();
#pragma unroll
  for (int r = 0; r < 32; r += 8)
    dst[((size_t)(roff + n0 + ty + r) << 10) + k0 + tx] = f2bf(tile[tx][ty + r]);
}

// ---------------- GEMM: C[M][N] = A[M][K] @ Bt[N][K]^T ----------------
DEV int swz(int row, int kb) { return (row << 7) + (kb ^ ((row & 7) << 4)); }

__global__ __launch_bounds__(256) void gemm_kernel(
    const u16* __restrict__ A, const u16* __restrict__ Bt, int K, int mode,
    const float* __restrict__ bias_cat, u16* __restrict__ qbuf, u16* __restrict__ kbuf,
    u16* __restrict__ vbuf, const float* __restrict__ bo, float* __restrict__ outp)
{
  __shared__ alignas(16) char ldsA[16384];
  __shared__ alignas(16) char ldsB[16384];
  const int tid = threadIdx.x;
  const int lane = tid & 63, wid = tid >> 6;
  const int l15 = lane & 15, lg = lane >> 4;
  const int wm = (wid >> 1) << 6, wn = (wid & 1) << 6;
  const size_t K_ = (size_t)K;
  const u16* Apan = A + (size_t)blockIdx.y * 128 * K_;
  const u16* Bpan = Bt + (size_t)blockIdx.x * 128 * K_;

  f32x4 acc[4][4];
  const f32x4 fz = {0.f, 0.f, 0.f, 0.f};
#pragma unroll
  for (int mt = 0; mt < 4; ++mt)
#pragma unroll
    for (int nt = 0; nt < 4; ++nt) acc[mt][nt] = fz;

  for (int k0 = 0; k0 < K; k0 += 64) {
#pragma unroll
    for (int i = 0; i < 4; ++i) {
      int cid = tid + i * 256;
      int r = cid >> 3, cbyte = (cid & 7) << 4;
      u16x8 va = *(const u16x8*)(Apan + (size_t)r * K_ + k0 + (cbyte >> 1));
      u16x8 vb = *(const u16x8*)(Bpan + (size_t)r * K_ + k0 + (cbyte >> 1));
      *(u16x8*)(ldsA + swz(r, cbyte)) = va;
      *(u16x8*)(ldsB + swz(r, cbyte)) = vb;
    }
    __syncthreads();
#pragma unroll
    for (int ks = 0; ks < 2; ++ks) {
      int kb = (ks << 6) + (lg << 4);
      bf16x8 af[4], bfr[4];
#pragma unroll
      for (int mt = 0; mt < 4; ++mt)
        af[mt] = *(const bf16x8*)(ldsA + swz(wm + mt * 16 + l15, kb));
#pragma unroll
      for (int nt = 0; nt < 4; ++nt)
        bfr[nt] = *(const bf16x8*)(ldsB + swz(wn + nt * 16 + l15, kb));
#pragma unroll
      for (int mt = 0; mt < 4; ++mt)
#pragma unroll
        for (int nt = 0; nt < 4; ++nt)
          acc[mt][nt] = __builtin_amdgcn_mfma_f32_16x16x32_bf16(af[mt], bfr[nt], acc[mt][nt], 0, 0, 0);
    }
    __syncthreads();
  }

  const int rb = blockIdx.y * 128 + wm + (lg << 2);
  const int cb = blockIdx.x * 128 + wn + l15;
#pragma unroll
  for (int mt = 0; mt < 4; ++mt) {
#pragma unroll
    for (int nt = 0; nt < 4; ++nt) {
      int c = cb + nt * 16;
      if (mode == 0) {
        float bias = bias_cat[c];
#pragma unroll
        for (int j = 0; j < 4; ++j) {
          int r = rb + mt * 16 + j;
          int b = r >> 11, t = r & 2047;
          u16 bv = f2bf(acc[mt][nt][j] + bias);
          if (c < 1024) {
            qbuf[(((size_t)((b << 4) + (c >> 6)) * 2048 + t) << 6) + (c & 63)] = bv;
          } else if (c < 1280) {
            kbuf[(((size_t)((b << 2) + ((c - 1024) >> 6)) * 2048 + t) << 6) + (c & 63)] = bv;
          } else {
            vbuf[(((size_t)((b << 2) + ((c - 1280) >> 6)) * 2048 + t) << 6) + (c & 63)] = bv;
          }
        }
      } else {
        float bias = bo[c];
#pragma unroll
        for (int j = 0; j < 4; ++j) {
          int r = rb + mt * 16 + j;
          outp[(size_t)r * 1024 + c] = acc[mt][nt][j] + bias;
        }
      }
    }
  }
}

// ---------------- rope (in-place, folds head_weights * 1/8 into q) ----------------
__global__ __launch_bounds__(256) void rope_kernel(
    u16* __restrict__ qbuf, u16* __restrict__ kbuf,
    const float* __restrict__ cosT, const float* __restrict__ sinT,
    const float* __restrict__ hw)
{
  int idx = blockIdx.x * 256 + threadIdx.x;
  const int NQ = 2 * 16 * 2048 * 32;
  const int NK = 2 * 4 * 2048 * 32;
  if (idx < NQ) {
    int d = idx & 31, r = idx >> 5;
    int t = r & 2047, h = (r >> 11) & 15;
    float wgt = hw[h] * 0.125f;
    u16* p = qbuf + ((size_t)r << 6);
    float x0 = bf2f(p[d]), x1 = bf2f(p[d + 32]);
    float ch = cosT[(t << 5) + d], sh = sinT[(t << 5) + d];
    p[d]      = f2bf((x0 * ch - x1 * sh) * wgt);
    p[d + 32] = f2bf((x1 * ch + x0 * sh) * wgt);
  } else if (idx < NQ + NK) {
    int e = idx - NQ;
    int d = e & 31, r = e >> 5, t = r & 2047;
    u16* p = kbuf + ((size_t)r << 6);
    float x0 = bf2f(p[d]), x1 = bf2f(p[d + 32]);
    float ch = cosT[(t << 5) + d], sh = sinT[(t << 5) + d];
    p[d]      = f2bf(x0 * ch - x1 * sh);
    p[d + 32] = f2bf(x1 * ch + x0 * sh);
  }
}

// ---------------- scalar attention: one wave per (b,h,row). Correct by construction. ----------------
__global__ __launch_bounds__(256) void attn_scalar_kernel(
    const u16* __restrict__ qbuf, const u16* __restrict__ kbuf,
    const u16* __restrict__ vbuf, u16* __restrict__ obuf)
{
  const int tid = threadIdx.x;
  const int lane = tid & 63, w = tid >> 6;
  const int gw = blockIdx.x * 4 + w;
  const int i = gw & 2047;
  const int h = (gw >> 11) & 15;
  const int b = gw >> 15;
  const int hkv = h >> 2;
  const u16* Qrow = qbuf + ((((size_t)(b * 16 + h)) * 2048 + i) << 6);
  const u16* Kp = kbuf + (((size_t)(b * 4 + hkv)) << 17);
  const u16* Vp = vbuf + (((size_t)(b * 4 + hkv)) << 17);

  float q[64];
#pragma unroll
  for (int dc = 0; dc < 8; ++dc) {
    u16x8 qv = *(const u16x8*)(Qrow + dc * 8);
#pragma unroll
    for (int e = 0; e < 8; ++e) q[dc * 8 + e] = bf2f(qv[e]);
  }

  float out, inv;
  if (i >= 8) {
    // 33 key slots: 8 globals + 25-wide window; window slot inactive if j<8 (dup) or j>=2048
    int j; bool act;
    if (lane < 8)       { j = lane; act = true; }
    else if (lane < 33) { j = i - 12 + (lane - 8); act = (j >= 8) && (j < 2048); }
    else                { j = 0; act = false; }
    int jc = j < 0 ? 0 : (j > 2047 ? 2047 : j);
    float s = -1e30f;
    if (act) {
      s = 0.f;
      const u16* Krow = Kp + ((size_t)jc << 6);
#pragma unroll
      for (int dc = 0; dc < 8; ++dc) {
        u16x8 kv = *(const u16x8*)(Krow + dc * 8);
#pragma unroll
        for (int e = 0; e < 8; ++e) s = fmaf(bf2f(kv[e]), q[dc * 8 + e], s);
      }
    }
    float m = s;
#pragma unroll
    for (int sh = 32; sh >= 1; sh >>= 1) m = fmaxf(m, __shfl_xor(m, sh));
    float p = act ? __expf(s - m) : 0.f;
    float l = p;
#pragma unroll
    for (int sh = 32; sh >= 1; sh >>= 1) l += __shfl_xor(l, sh);
    float o = 0.f;
    for (int t = 0; t < 33; ++t) {
      float pt = __shfl(p, t);
      int jt = __shfl(jc, t);
      o = fmaf(pt, bf2f(Vp[((size_t)jt << 6) + lane]), o);
    }
    out = o; inv = 1.f / l;
  } else {
    // global row: full attention over all 2048 keys, online softmax in 32 chunks
    float m = -1e30f, l = 0.f, o = 0.f;
    for (int c = 0; c < 32; ++c) {
      int j = (c << 6) + lane;
      const u16* Krow = Kp + ((size_t)j << 6);
      float s = 0.f;
#pragma unroll
      for (int dc = 0; dc < 8; ++dc) {
        u16x8 kv = *(const u16x8*)(Krow + dc * 8);
#pragma unroll
        for (int e = 0; e < 8; ++e) s = fmaf(bf2f(kv[e]), q[dc * 8 + e], s);
      }
      float cm = s;
#pragma unroll
      for (int sh = 32; sh >= 1; sh >>= 1) cm = fmaxf(cm, __shfl_xor(cm, sh));
      float nm = fmaxf(m, cm);
      float sc = __expf(m - nm);
      float p = __expf(s - nm);
      float ps = p;
#pragma unroll
      for (int sh = 32; sh >= 1; sh >>= 1) ps += __shfl_xor(ps, sh);
      l = l * sc + ps;
      o *= sc;
      m = nm;
      for (int t = 0; t < 64; ++t) {
        float pt = __shfl(p, t);
        o = fmaf(pt, bf2f(Vp[(((size_t)(c << 6) + t) << 6) + lane]), o);
      }
    }
    out = o; inv = 1.f / l;
  }
  obuf[(((size_t)(b * 2048 + i)) << 10) + h * 64 + lane] = f2bf(out * inv);
}

extern "C" void kernel_launch(void* const* d_in, const int* in_sizes, int n_in,
                              void* d_out, int out_size, void* d_ws, size_t ws_size,
                              hipStream_t stream) {
  const float* x  = (const float*)d_in[0];
  const float* Wq = (const float*)d_in[1];
  const float* bq = (const float*)d_in[2];
  const float* Wk = (const float*)d_in[3];
  const float* bk = (const float*)d_in[4];
  const float* Wv = (const float*)d_in[5];
  const float* bv = (const float*)d_in[6];
  const float* Wo = (const float*)d_in[7];
  const float* bo = (const float*)d_in[8];
  const float* hw = (const float*)d_in[9];
  float* out = (float*)d_out;

  char* ws = (char*)d_ws;
  size_t off = 0;
  auto alloc = [&](size_t bytes) { char* p = ws + off; off += (bytes + 255) & ~(size_t)255; return p; };
  u16* xbf    = (u16*)alloc((size_t)4096 * 1024 * 2);   // also reused as obuf
  u16* wcat   = (u16*)alloc((size_t)1536 * 1024 * 2);
  u16* wot    = (u16*)alloc((size_t)1024 * 1024 * 2);
  float* biascat = (float*)alloc(1536 * 4);
  float* cosT = (float*)alloc(65536 * 4);
  float* sinT = (float*)alloc(65536 * 4);
  u16* qbuf   = (u16*)alloc((size_t)2 * 16 * 2048 * 64 * 2);
  u16* kbuf   = (u16*)alloc((size_t)2 * 4 * 2048 * 64 * 2);
  u16* vbuf   = (u16*)alloc((size_t)2 * 4 * 2048 * 64 * 2);
  u16* obuf   = xbf;  // xbf dead after first GEMM

  prep_kernel<<<4358, 256, 0, stream>>>(x, bq, bk, bv, biascat, cosT, sinT, xbf);
  wtrans_kernel<<<dim3(32, 32, 4), 256, 0, stream>>>(Wq, Wk, Wv, Wo, wcat, wot);
  gemm_kernel<<<dim3(12, 32), 256, 0, stream>>>(xbf, wcat, 1024, 0, biascat, qbuf, kbuf, vbuf, nullptr, nullptr);
  rope_kernel<<<10240, 256, 0, stream>>>(qbuf, kbuf, cosT, sinT, hw);
  attn_scalar_kernel<<<16384, 256, 0, stream>>>(qbuf, kbuf, vbuf, obuf);
  gemm_kernel<<<dim3(8, 32), 256, 0, stream>>>(obuf, wot, 1024, 1, nullptr, nullptr, nullptr, nullptr, bo, out);
}